// Round 1
// baseline (116.111 us; speedup 1.0000x reference)
//
#include <hip/hip_runtime.h>
#include <math.h>

// Problem constants (B=2, C=64, H=W=64)
#define BB  2
#define CC  64
#define HH  64
#define WW  64
#define PP  4096           // H*W
#define CHW 262144         // C*H*W
#define HW2 1024           // 32*32 downsampled plane
#define NSLOT 289          // 17*17 window
#define KMAX 16

// workspace layout in floats
#define OFF_XD   0
#define SZ_XD    (BB*CC*HW2)          // 131072
#define OFF_XN   (OFF_XD + SZ_XD)     // normalized features, pixel-major (B,P,C)
#define SZ_BPC   (BB*PP*CC)           // 524288
#define OFF_XT   (OFF_XN + SZ_BPC)    // raw features, pixel-major
#define OFF_ENH  (OFF_XT + SZ_BPC)    // enh = agg + LN, pixel-major
#define OFF_DF   (OFF_ENH + SZ_BPC)   // B*P
#define OFF_MM   (OFF_DF + BB*PP)     // 4 ints: {min0,max0,min1,max1}

__global__ void k_init(int* mm) {
    int t = threadIdx.x;
    if (t < BB) { mm[t*2] = 0x7FFFFFFF; mm[t*2+1] = 0; }
}

// 2x2 mean downsample: xd[b,c,hh,ww]
__global__ void k_down(const float* __restrict__ x, float* __restrict__ xd) {
    int t = blockIdx.x*256 + threadIdx.x;     // < 131072
    int ww = t & 31, hh = (t>>5)&31, c = (t>>10)&63, b = t>>16;
    const float* xp = x + ((b*CC + c)*HH + hh*2)*WW + ww*2;
    xd[t] = (xp[0] + xp[1] + xp[WW] + xp[WW+1]) * 0.25f;
}

// per-pixel: df (|x - upsample2x(down2x(x))| summed over C), norm, write xn/xt
// pixel-major; block-level min/max of df -> device atomics (nonneg float as int)
__global__ __launch_bounds__(256) void k_prep(const float* __restrict__ x,
        const float* __restrict__ xd, float* __restrict__ xn,
        float* __restrict__ xt, float* __restrict__ df, int* __restrict__ mm) {
    int bp = blockIdx.x*256 + threadIdx.x;    // < 8192
    int b = bp >> 12, p = bp & 4095, y = p >> 6, xx = p & 63;
    // upsample taps: even out idx i=2m: src=m-0.25 -> i0=m-1 (clamped), i1=m, t=0.75
    //                odd  out idx i=2m+1: src=m+0.25 -> i0=m, i1=m+1 (clamped), t=0.25
    int m = y >> 1, iy0, iy1; float ty;
    if ((y & 1) == 0) { iy0 = m > 0 ? m-1 : 0; iy1 = m; ty = 0.75f; }
    else              { iy0 = m; iy1 = m < 31 ? m+1 : 31; ty = 0.25f; }
    int n = xx >> 1, jx0, jx1; float tx;
    if ((xx & 1) == 0) { jx0 = n > 0 ? n-1 : 0; jx1 = n; tx = 0.75f; }
    else               { jx0 = n; jx1 = n < 31 ? n+1 : 31; tx = 0.25f; }
    const float* xb  = x  + b*CHW + p;
    const float* xdb = xd + b*CC*HW2;
    float dfa = 0.f, ss = 0.f;
    for (int c = 0; c < CC; ++c) {
        float v = xb[c*PP];
        const float* xdc = xdb + c*HW2;
        float a00 = xdc[iy0*32 + jx0], a10 = xdc[iy1*32 + jx0];
        float a01 = xdc[iy0*32 + jx1], a11 = xdc[iy1*32 + jx1];
        float r0 = a00*(1.f-ty) + a10*ty;        // h-lerp first (matches ref order)
        float r1 = a01*(1.f-ty) + a11*ty;
        float xu = r0*(1.f-tx) + r1*tx;
        dfa += fabsf(v - xu);
        ss  += v*v;
    }
    df[bp] = dfa;
    float inv = 1.f / fmaxf(sqrtf(ss), 1e-12f);
    float* xnp = xn + bp*64; float* xtp = xt + bp*64;
    for (int c = 0; c < CC; ++c) {
        float v = xb[c*PP];
        xnp[c] = v * inv;
        xtp[c] = v;
    }
    // block reduce min/max (block spans a single batch: 16 blocks per batch)
    float mn = dfa, mx = dfa;
    #pragma unroll
    for (int off = 1; off < 64; off <<= 1) {
        mn = fminf(mn, __shfl_xor(mn, off));
        mx = fmaxf(mx, __shfl_xor(mx, off));
    }
    __shared__ float smn[4], smx[4];
    int wave = threadIdx.x >> 6, lane = threadIdx.x & 63;
    if (lane == 0) { smn[wave] = mn; smx[wave] = mx; }
    __syncthreads();
    if (threadIdx.x == 0) {
        float m0 = fminf(fminf(smn[0],smn[1]), fminf(smn[2],smn[3]));
        float m1 = fmaxf(fmaxf(smx[0],smx[1]), fmaxf(smx[2],smx[3]));
        atomicMin(&mm[b*2],   __float_as_int(m0));   // df >= 0: int order == float order
        atomicMax(&mm[b*2+1], __float_as_int(m1));
    }
}

// Core: one wave per pixel (4 waves/block). 289 sims -> top16 -> softmax agg -> +LN
__global__ __launch_bounds__(256) void k_sim(const float* __restrict__ xn,
        const float* __restrict__ xt, const float* __restrict__ df,
        const int* __restrict__ mm, const float* __restrict__ gamma,
        const float* __restrict__ beta, float* __restrict__ enh) {
    __shared__ float sims[4][320];
    int wave = threadIdx.x >> 6, lane = threadIdx.x & 63;
    int bp = blockIdx.x*4 + wave;
    int b = bp >> 12, p = bp & 4095, y = p >> 6, xx = p & 63;
    int cg = lane & 15, qs = lane >> 4;       // 16 channel-groups x 4 neighbor-slots
    float4 c4 = *(const float4*)(xn + bp*64 + cg*4);
    if (lane < 31) sims[wave][NSLOT + lane] = -1e30f;   // pad 289..319
    // ---- phase A: sims (4 neighbors per iteration) ----
    for (int it = 0; it < 73; ++it) {
        int s = it*4 + qs;                     // slot 0..291
        int a = s / 17;
        int dy = a - 8, dx = (s - a*17) - 8;
        int ny = y + dy, nx = xx + dx;
        bool valid = (s < NSLOT) && (ny >= 0) && (ny < HH) && (nx >= 0) && (nx < WW);
        float pd = 0.f;
        if (valid) {
            int q = (b << 12) + ny*64 + nx;
            float4 n4 = *(const float4*)(xn + q*64 + cg*4);
            pd = c4.x*n4.x + c4.y*n4.y + c4.z*n4.z + c4.w*n4.w;
        }
        pd += __shfl_xor(pd, 1);
        pd += __shfl_xor(pd, 2);
        pd += __shfl_xor(pd, 4);
        pd += __shfl_xor(pd, 8);
        if (cg == 0 && s < NSLOT) sims[wave][s] = valid ? pd : -1e30f;
    }
    __syncthreads();
    // ---- phase B: top-16 by iterative wave-max (ties -> lowest index, like lax.top_k) ----
    float tv[5]; int ti[5];
    #pragma unroll
    for (int j = 0; j < 5; ++j) { tv[j] = sims[wave][lane + 64*j]; ti[j] = lane + 64*j; }
    float top_v[KMAX]; int top_s[KMAX];
    #pragma unroll
    for (int r = 0; r < KMAX; ++r) {
        float bv = tv[0]; int bi = ti[0];
        #pragma unroll
        for (int j = 1; j < 5; ++j) {
            bool take = (tv[j] > bv) || (tv[j] == bv && ti[j] < bi);
            if (take) { bv = tv[j]; bi = ti[j]; }
        }
        #pragma unroll
        for (int off = 32; off >= 1; off >>= 1) {
            float ov = __shfl_xor(bv, off); int oi = __shfl_xor(bi, off);
            bool take = (ov > bv) || (ov == bv && oi < bi);
            if (take) { bv = ov; bi = oi; }
        }
        top_v[r] = bv; top_s[r] = bi;          // uniform across wave
        #pragma unroll
        for (int j = 0; j < 5; ++j) if (ti[j] == bi) tv[j] = -3e30f;
    }
    // ---- phase C: k, softmax weights over top-k, aggregate raw feats ----
    float dmin = __int_as_float(mm[b*2]);
    float dmax = __int_as_float(mm[b*2+1]);
    float dn = (df[bp] - dmin) / (dmax - dmin + 1e-8f);
    int kk = 1 + (int)rintf(dn * 15.f);        // round-half-even matches jnp.round
    float e[KMAX]; float S = 0.f;
    #pragma unroll
    for (int i = 0; i < KMAX; ++i) { e[i] = (i < kk) ? expf(top_v[i]) : 0.f; S += e[i]; }
    float acc = 0.f;
    #pragma unroll
    for (int i = 0; i < KMAX; ++i) {
        if (i < kk) {
            int s = top_s[i];
            int a = s / 17;
            int q = (b << 12) + (y + a - 8)*64 + (xx + (s - a*17) - 8);
            acc += (e[i] / S) * xt[q*64 + lane];   // lane = channel, coalesced 256B
        }
    }
    // ---- phase D: LayerNorm over C and enh = agg + xln ----
    float xv = xt[bp*64 + lane];
    float mu = xv;
    #pragma unroll
    for (int off = 1; off < 64; off <<= 1) mu += __shfl_xor(mu, off);
    mu *= (1.f/64.f);
    float d = xv - mu;
    float vs = d*d;
    #pragma unroll
    for (int off = 1; off < 64; off <<= 1) vs += __shfl_xor(vs, off);
    float var = vs * (1.f/64.f);
    float xln = d / sqrtf(var + 1e-5f) * gamma[lane] + beta[lane];
    enh[bp*64 + lane] = acc + xln;
}

// FFN: 32 pixels/block; enh(32x64) @ w1^T -> relu -> h1(32x128) @ w2^T; out = enh+ffn
__global__ __launch_bounds__(256) void k_ffn(const float* __restrict__ enh,
        const float* __restrict__ w1, const float* __restrict__ b1,
        const float* __restrict__ w2, const float* __restrict__ b2,
        float* __restrict__ out) {
    __shared__ float w1t[64*129];   // [c][d], padded stride
    __shared__ float enhT[32*65];   // [px][c]
    __shared__ float h1s[32*129];   // [px][d]
    int t = threadIdx.x;
    int bp0 = blockIdx.x * 32;
    for (int i = t; i < 8192; i += 256) { int d = i >> 6, c = i & 63; w1t[c*129 + d] = w1[i]; }
    for (int i = t; i < 2048; i += 256) { int px = i >> 6, c = i & 63; enhT[px*65 + c] = enh[bp0*64 + i]; }
    __syncthreads();
    int pxg = t & 7, dg = t >> 3;
    int px0 = pxg*4, d0 = dg*4;
    // GEMM1: h1 = relu(enh @ w1^T + b1)
    float acc[4][4] = {};
    for (int k = 0; k < 64; ++k) {
        float a0 = enhT[(px0+0)*65 + k], a1 = enhT[(px0+1)*65 + k];
        float a2 = enhT[(px0+2)*65 + k], a3 = enhT[(px0+3)*65 + k];
        float b0 = w1t[k*129 + d0+0], w1b = w1t[k*129 + d0+1];
        float b2v = w1t[k*129 + d0+2], b3 = w1t[k*129 + d0+3];
        acc[0][0] += a0*b0; acc[0][1] += a0*w1b; acc[0][2] += a0*b2v; acc[0][3] += a0*b3;
        acc[1][0] += a1*b0; acc[1][1] += a1*w1b; acc[1][2] += a1*b2v; acc[1][3] += a1*b3;
        acc[2][0] += a2*b0; acc[2][1] += a2*w1b; acc[2][2] += a2*b2v; acc[2][3] += a2*b3;
        acc[3][0] += a3*b0; acc[3][1] += a3*w1b; acc[3][2] += a3*b2v; acc[3][3] += a3*b3;
    }
    float bia[4] = { b1[d0], b1[d0+1], b1[d0+2], b1[d0+3] };
    #pragma unroll
    for (int i = 0; i < 4; ++i)
        #pragma unroll
        for (int j = 0; j < 4; ++j)
            h1s[(px0+i)*129 + d0+j] = fmaxf(acc[i][j] + bia[j], 0.f);
    __syncthreads();
    // GEMM2: ffn = h1 @ w2^T + b2 ; w2 rows read from global as float4 (broadcast in wave)
    int c0 = dg*2;
    const float4* w2v = (const float4*)w2;       // w2[c][d] row-major, 32 float4 per row
    float acc2[4][2] = {};
    for (int k4 = 0; k4 < 32; ++k4) {
        float4 wa = w2v[(c0+0)*32 + k4];
        float4 wb = w2v[(c0+1)*32 + k4];
        #pragma unroll
        for (int i = 0; i < 4; ++i) {
            const float* hp = &h1s[(px0+i)*129 + k4*4];
            float h0 = hp[0], h1v = hp[1], h2 = hp[2], h3 = hp[3];
            acc2[i][0] += h0*wa.x; acc2[i][0] += h1v*wa.y; acc2[i][0] += h2*wa.z; acc2[i][0] += h3*wa.w;
            acc2[i][1] += h0*wb.x; acc2[i][1] += h1v*wb.y; acc2[i][1] += h2*wb.z; acc2[i][1] += h3*wb.w;
        }
    }
    int b = bp0 >> 12, pbase = (bp0 & 4095) + px0;
    #pragma unroll
    for (int j = 0; j < 2; ++j) {
        float bb2 = b2[c0+j];
        #pragma unroll
        for (int i = 0; i < 4; ++i) {
            float val = enhT[(px0+i)*65 + (c0+j)] + (acc2[i][j] + bb2);
            out[b*CHW + (c0+j)*PP + pbase + i] = val;
        }
    }
}

extern "C" void kernel_launch(void* const* d_in, const int* in_sizes, int n_in,
                              void* d_out, int out_size, void* d_ws, size_t ws_size,
                              hipStream_t stream) {
    const float* x     = (const float*)d_in[0];
    const float* gamma = (const float*)d_in[1];
    const float* beta  = (const float*)d_in[2];
    const float* w1    = (const float*)d_in[3];
    const float* b1    = (const float*)d_in[4];
    const float* w2    = (const float*)d_in[5];
    const float* b2    = (const float*)d_in[6];
    float* ws  = (float*)d_ws;
    float* xd  = ws + OFF_XD;
    float* xn  = ws + OFF_XN;
    float* xt  = ws + OFF_XT;
    float* enh = ws + OFF_ENH;
    float* df  = ws + OFF_DF;
    int*   mm  = (int*)(ws + OFF_MM);
    float* out = (float*)d_out;

    k_init<<<1, 64, 0, stream>>>(mm);
    k_down<<<512, 256, 0, stream>>>(x, xd);
    k_prep<<<32, 256, 0, stream>>>(x, xd, xn, xt, df, mm);
    k_sim<<<2048, 256, 0, stream>>>(xn, xt, df, mm, gamma, beta, enh);
    k_ffn<<<256, 256, 0, stream>>>(enh, w1, b1, w2, b2, out);
}

// Round 2
// 81.244 us; speedup vs baseline: 1.4292x; 1.4292x over previous
//
#include <hip/hip_runtime.h>
#include <math.h>

// Problem constants (B=2, C=64, H=W=64)
#define BB  2
#define CC  64
#define HH  64
#define WW  64
#define PP  4096           // H*W
#define CHW 262144         // C*H*W
#define HW2 1024           // 32*32 downsampled plane
#define SIMP 292           // padded sims row (289 used)
#define KMAX 16

// workspace layout in floats
#define OFF_XD   0
#define OFF_XT   131072                    // raw features, pixel-major (B,P,C)
#define OFF_SIMS 655360                    // 8192 x 292
#define OFF_ENH  (OFF_SIMS + 8192*SIMP)    // enh, pixel-major
#define OFF_DF   (OFF_ENH + 524288)
#define OFF_INV  (OFF_DF + 8192)
#define OFF_MM   (OFF_INV + 8192)          // 4 ints

__global__ void k_init(int* mm) {
    int t = threadIdx.x;
    if (t < BB) { mm[t*2] = 0x7FFFFFFF; mm[t*2+1] = 0; }
}

// 2x2 mean downsample
__global__ void k_down(const float* __restrict__ x, float* __restrict__ xd) {
    int t = blockIdx.x*256 + threadIdx.x;     // < 131072
    int ww = t & 31, hh = (t>>5)&31, c = (t>>10)&63, b = t>>16;
    const float* xp = x + ((b*CC + c)*HH + hh*2)*WW + ww*2;
    xd[t] = (xp[0] + xp[1] + xp[WW] + xp[WW+1]) * 0.25f;
}

// per-32-pixel block: transpose x -> xt (pixel-major), df, inv-norm, minmax atomics
__global__ __launch_bounds__(256) void k_prep(const float* __restrict__ x,
        const float* __restrict__ xd, float* __restrict__ xt,
        float* __restrict__ df, float* __restrict__ invn, int* __restrict__ mm) {
    __shared__ float T[64*33];
    __shared__ float pdf[8*33], pss[8*33];
    int t = threadIdx.x;
    int bp0 = blockIdx.x * 32;                // 256 blocks
    int b = bp0 >> 12, p0 = bp0 & 4095;
    int y = p0 >> 6, x0 = p0 & 63;
    const float* xb = x + b*CHW + p0;
    #pragma unroll
    for (int i = 0; i < 8; ++i) {
        int idx = t + i*256;                  // 2048 = 64c x 32px
        int c = idx >> 5, pxl = idx & 31;
        T[c*33 + pxl] = xb[c*PP + pxl];
    }
    __syncthreads();
    // df/ss partials: px = t&31, slice = t>>5 covers 8 channels
    int px = t & 31, sl = t >> 5;
    int xxp = x0 + px;
    int m = y >> 1, iy0, iy1; float ty;
    if ((y & 1) == 0) { iy0 = m > 0 ? m-1 : 0; iy1 = m; ty = 0.75f; }
    else              { iy0 = m; iy1 = m < 31 ? m+1 : 31; ty = 0.25f; }
    int n2 = xxp >> 1, jx0, jx1; float tx;
    if ((xxp & 1) == 0) { jx0 = n2 > 0 ? n2-1 : 0; jx1 = n2; tx = 0.75f; }
    else                { jx0 = n2; jx1 = n2 < 31 ? n2+1 : 31; tx = 0.25f; }
    const float* xdb = xd + b*CC*HW2;
    float dfa = 0.f, ss = 0.f;
    #pragma unroll
    for (int ci = 0; ci < 8; ++ci) {
        int c = sl*8 + ci;
        const float* xdc = xdb + c*HW2;
        float a00 = xdc[iy0*32+jx0], a10 = xdc[iy1*32+jx0];
        float a01 = xdc[iy0*32+jx1], a11 = xdc[iy1*32+jx1];
        float r0 = a00*(1.f-ty) + a10*ty;
        float r1 = a01*(1.f-ty) + a11*ty;
        float xu = r0*(1.f-tx) + r1*tx;
        float v = T[c*33 + px];
        dfa += fabsf(v - xu);
        ss  += v*v;
    }
    pdf[sl*33 + px] = dfa; pss[sl*33 + px] = ss;
    __syncthreads();
    if (t < 32) {
        float d = 0.f, s = 0.f;
        #pragma unroll
        for (int q = 0; q < 8; ++q) { d += pdf[q*33 + t]; s += pss[q*33 + t]; }
        df[bp0 + t] = d;
        invn[bp0 + t] = 1.f / fmaxf(sqrtf(s), 1e-12f);
        float mn = d, mx = d;
        #pragma unroll
        for (int off = 1; off < 32; off <<= 1) {
            mn = fminf(mn, __shfl_xor(mn, off));
            mx = fmaxf(mx, __shfl_xor(mx, off));
        }
        if (t == 0) {
            atomicMin(&mm[b*2],   __float_as_int(mn));
            atomicMax(&mm[b*2+1], __float_as_int(mx));
        }
    }
    __syncthreads();
    // write xt pixel-major, lane = channel (contiguous 256B per pixel)
    int c = t & 63, pg = t >> 6;
    #pragma unroll
    for (int ii = 0; ii < 8; ++ii) {
        int p = pg*8 + ii;
        xt[(bp0 + p)*64 + c] = T[c*33 + p];
    }
}

// Tiled GEMM: 8x8 pixel tile vs 64-neighbor chunk, K=64. sim = dot*invA*invB
// grid = 128 tiles * 9 chunks
__global__ __launch_bounds__(256) void k_simA(const float* __restrict__ xt,
        const float* __restrict__ invn, float* __restrict__ sims) {
    __shared__ float A[64*68];
    __shared__ float Bs[64*68];
    __shared__ float sInvA[64], sInvB[64];
    int t = threadIdx.x;
    int bid = blockIdx.x;
    int tile = bid / 9, chunk = bid - tile*9;
    int b = tile >> 6, trow = (tile >> 3) & 7, tcol = tile & 7;
    int y0 = trow*8, x0 = tcol*8;
    int pbase = (b<<12) + y0*64 + x0;
    // stage A (pixel tile), XOR-swizzled slots
    #pragma unroll
    for (int kq = 0; kq < 4; ++kq) {
        int q = t + kq*256;
        int px = q >> 4, c4 = q & 15;
        int i = px >> 3, j = px & 7;
        int bp = pbase + i*64 + j;
        float4 v = *(const float4*)(xt + bp*64 + c4*4);
        int slot = c4 ^ ((px >> 2) & 7);
        *(float4*)&A[px*68 + slot*4] = v;
        if (c4 == 0) sInvA[px] = invn[bp];
    }
    // stage B (neighbor chunk: 16 col-groups of 4)
    #pragma unroll
    for (int kq = 0; kq < 4; ++kq) {
        int q = t + kq*256;
        int n = q >> 4, c4 = q & 15;
        int G = chunk*16 + (n >> 2);
        int r = G / 6, cg = G - r*6;
        int cc = cg*4 + (n & 3);
        int ny = y0 + r - 8, nx = x0 + cc - 8;
        bool vimg = (ny >= 0) && (ny < HH) && (nx >= 0) && (nx < WW);
        float4 v = make_float4(0.f,0.f,0.f,0.f);
        int bq = (b<<12) + ny*64 + nx;
        if (vimg) v = *(const float4*)(xt + bq*64 + c4*4);
        int slot = c4 ^ ((n >> 2) & 7);
        *(float4*)&Bs[n*68 + slot*4] = v;
        if (c4 == 0) sInvB[n] = vimg ? invn[bq] : 0.f;
    }
    __syncthreads();
    int u = t & 15, g = t >> 4;
    int px0 = u*4, n0 = g*4;
    float acc[4][4] = {};
    #pragma unroll 4
    for (int k4 = 0; k4 < 16; ++k4) {
        int sa = (k4 ^ (u & 7)) << 2;
        int sb = (k4 ^ (g & 7)) << 2;
        float4 a0 = *(float4*)&A[(px0+0)*68 + sa];
        float4 a1 = *(float4*)&A[(px0+1)*68 + sa];
        float4 a2 = *(float4*)&A[(px0+2)*68 + sa];
        float4 a3 = *(float4*)&A[(px0+3)*68 + sa];
        float4 b0 = *(float4*)&Bs[(n0+0)*68 + sb];
        float4 b1 = *(float4*)&Bs[(n0+1)*68 + sb];
        float4 b2 = *(float4*)&Bs[(n0+2)*68 + sb];
        float4 b3 = *(float4*)&Bs[(n0+3)*68 + sb];
        #define FMA4(i,j,av,bv) acc[i][j] += av.x*bv.x + av.y*bv.y + av.z*bv.z + av.w*bv.w
        FMA4(0,0,a0,b0); FMA4(0,1,a0,b1); FMA4(0,2,a0,b2); FMA4(0,3,a0,b3);
        FMA4(1,0,a1,b0); FMA4(1,1,a1,b1); FMA4(1,2,a1,b2); FMA4(1,3,a1,b3);
        FMA4(2,0,a2,b0); FMA4(2,1,a2,b1); FMA4(2,2,a2,b2); FMA4(2,3,a2,b3);
        FMA4(3,0,a3,b0); FMA4(3,1,a3,b1); FMA4(3,2,a3,b2); FMA4(3,3,a3,b3);
        #undef FMA4
    }
    float invA[4], invB[4];
    #pragma unroll
    for (int i = 0; i < 4; ++i) { invA[i] = sInvA[px0+i]; invB[i] = sInvB[n0+i]; }
    __syncthreads();                 // A reads done; reuse A as C buffer
    #pragma unroll
    for (int i = 0; i < 4; ++i) {
        float4 w;
        w.x = acc[i][0]*invA[i]*invB[0];
        w.y = acc[i][1]*invA[i]*invB[1];
        w.z = acc[i][2]*invA[i]*invB[2];
        w.w = acc[i][3]*invA[i]*invB[3];
        *(float4*)&A[(px0+i)*68 + n0] = w;
    }
    __syncthreads();
    // write-out: each wave handles 16 pixels; lane = local neighbor id
    int wave = t >> 6, lane = t & 63;
    for (int ii = 0; ii < 16; ++ii) {
        int pxl = wave*16 + ii;
        int i_loc = pxl >> 3, j_loc = pxl & 7;
        int bp = pbase + i_loc*64 + j_loc;
        float val = A[pxl*68 + lane];
        int G = chunk*16 + (lane >> 2);
        int r = G / 6, cg = G - r*6;
        int cc = cg*4 + (lane & 3);
        int sy = r - i_loc, sx = cc - j_loc;
        if (sy >= 0 && sy <= 16 && sx >= 0 && sx <= 16) {
            int ny = y0 + r - 8, nx = x0 + cc - 8;
            bool vimg = ((ny | nx) >= 0) && (ny < HH) && (nx < WW);
            sims[bp*SIMP + sy*17 + sx] = vimg ? val : -1e30f;
        }
    }
}

// wave per pixel: top16 -> softmax agg -> +LN
__global__ __launch_bounds__(256) void k_simB(const float* __restrict__ sims,
        const float* __restrict__ xt, const float* __restrict__ df,
        const int* __restrict__ mm, const float* __restrict__ gamma,
        const float* __restrict__ beta, float* __restrict__ enh) {
    int wave = threadIdx.x >> 6, lane = threadIdx.x & 63;
    int bp = blockIdx.x*4 + wave;
    int b = bp >> 12, p = bp & 4095, y = p >> 6, xx = p & 63;
    const float* srow = sims + bp*SIMP;
    float tv[5]; int ti[5];
    #pragma unroll
    for (int j = 0; j < 5; ++j) {
        int idx = lane + 64*j;
        tv[j] = (idx < 289) ? srow[idx] : -1e30f;
        ti[j] = idx;
    }
    float top_v[KMAX]; int top_s[KMAX];
    #pragma unroll
    for (int r = 0; r < KMAX; ++r) {
        float bv = tv[0]; int bi = ti[0];
        #pragma unroll
        for (int j = 1; j < 5; ++j) {
            bool take = (tv[j] > bv) || (tv[j] == bv && ti[j] < bi);
            if (take) { bv = tv[j]; bi = ti[j]; }
        }
        #pragma unroll
        for (int off = 32; off >= 1; off >>= 1) {
            float ov = __shfl_xor(bv, off); int oi = __shfl_xor(bi, off);
            bool take = (ov > bv) || (ov == bv && oi < bi);
            if (take) { bv = ov; bi = oi; }
        }
        top_v[r] = bv; top_s[r] = bi;
        #pragma unroll
        for (int j = 0; j < 5; ++j) if (ti[j] == bi) tv[j] = -3e30f;
    }
    float dmin = __int_as_float(mm[b*2]);
    float dmax = __int_as_float(mm[b*2+1]);
    float dn = (df[bp] - dmin) / (dmax - dmin + 1e-8f);
    int kk = 1 + (int)rintf(dn * 15.f);
    float e[KMAX]; float S = 0.f;
    #pragma unroll
    for (int i = 0; i < KMAX; ++i) { e[i] = (i < kk) ? expf(top_v[i]) : 0.f; S += e[i]; }
    float acc = 0.f;
    #pragma unroll
    for (int i = 0; i < KMAX; ++i) {
        if (i < kk) {
            int s = top_s[i];
            int a = s / 17;
            int q = (b << 12) + (y + a - 8)*64 + (xx + (s - a*17) - 8);
            acc += (e[i] / S) * xt[q*64 + lane];
        }
    }
    float xv = xt[bp*64 + lane];
    float mu = xv;
    #pragma unroll
    for (int off = 1; off < 64; off <<= 1) mu += __shfl_xor(mu, off);
    mu *= (1.f/64.f);
    float d = xv - mu;
    float vs = d*d;
    #pragma unroll
    for (int off = 1; off < 64; off <<= 1) vs += __shfl_xor(vs, off);
    float var = vs * (1.f/64.f);
    float xln = d / sqrtf(var + 1e-5f) * gamma[lane] + beta[lane];
    enh[bp*64 + lane] = acc + xln;
}

// FFN: 32 pixels/block; enh(32x64) @ w1^T -> relu -> h1(32x128) @ w2^T; out = enh+ffn
__global__ __launch_bounds__(256) void k_ffn(const float* __restrict__ enh,
        const float* __restrict__ w1, const float* __restrict__ b1,
        const float* __restrict__ w2, const float* __restrict__ b2,
        float* __restrict__ out) {
    __shared__ float w1t[64*129];
    __shared__ float enhT[32*65];
    __shared__ float h1s[32*129];
    int t = threadIdx.x;
    int bp0 = blockIdx.x * 32;
    for (int i = t; i < 8192; i += 256) { int d = i >> 6, c = i & 63; w1t[c*129 + d] = w1[i]; }
    for (int i = t; i < 2048; i += 256) { int px = i >> 6, c = i & 63; enhT[px*65 + c] = enh[bp0*64 + i]; }
    __syncthreads();
    int pxg = t & 7, dg = t >> 3;
    int px0 = pxg*4, d0 = dg*4;
    float acc[4][4] = {};
    for (int k = 0; k < 64; ++k) {
        float a0 = enhT[(px0+0)*65 + k], a1 = enhT[(px0+1)*65 + k];
        float a2 = enhT[(px0+2)*65 + k], a3 = enhT[(px0+3)*65 + k];
        float b0 = w1t[k*129 + d0+0], w1b = w1t[k*129 + d0+1];
        float b2v = w1t[k*129 + d0+2], b3 = w1t[k*129 + d0+3];
        acc[0][0] += a0*b0; acc[0][1] += a0*w1b; acc[0][2] += a0*b2v; acc[0][3] += a0*b3;
        acc[1][0] += a1*b0; acc[1][1] += a1*w1b; acc[1][2] += a1*b2v; acc[1][3] += a1*b3;
        acc[2][0] += a2*b0; acc[2][1] += a2*w1b; acc[2][2] += a2*b2v; acc[2][3] += a2*b3;
        acc[3][0] += a3*b0; acc[3][1] += a3*w1b; acc[3][2] += a3*b2v; acc[3][3] += a3*b3;
    }
    float bia[4] = { b1[d0], b1[d0+1], b1[d0+2], b1[d0+3] };
    #pragma unroll
    for (int i = 0; i < 4; ++i)
        #pragma unroll
        for (int j = 0; j < 4; ++j)
            h1s[(px0+i)*129 + d0+j] = fmaxf(acc[i][j] + bia[j], 0.f);
    __syncthreads();
    int c0 = dg*2;
    const float4* w2v = (const float4*)w2;
    float acc2[4][2] = {};
    for (int k4 = 0; k4 < 32; ++k4) {
        float4 wa = w2v[(c0+0)*32 + k4];
        float4 wb = w2v[(c0+1)*32 + k4];
        #pragma unroll
        for (int i = 0; i < 4; ++i) {
            const float* hp = &h1s[(px0+i)*129 + k4*4];
            float h0 = hp[0], h1v = hp[1], h2 = hp[2], h3 = hp[3];
            acc2[i][0] += h0*wa.x; acc2[i][0] += h1v*wa.y; acc2[i][0] += h2*wa.z; acc2[i][0] += h3*wa.w;
            acc2[i][1] += h0*wb.x; acc2[i][1] += h1v*wb.y; acc2[i][1] += h2*wb.z; acc2[i][1] += h3*wb.w;
        }
    }
    int b = bp0 >> 12, pbase = (bp0 & 4095) + px0;
    #pragma unroll
    for (int j = 0; j < 2; ++j) {
        float bb2 = b2[c0+j];
        #pragma unroll
        for (int i = 0; i < 4; ++i) {
            float val = enhT[(px0+i)*65 + (c0+j)] + (acc2[i][j] + bb2);
            out[b*CHW + (c0+j)*PP + pbase + i] = val;
        }
    }
}

extern "C" void kernel_launch(void* const* d_in, const int* in_sizes, int n_in,
                              void* d_out, int out_size, void* d_ws, size_t ws_size,
                              hipStream_t stream) {
    const float* x     = (const float*)d_in[0];
    const float* gamma = (const float*)d_in[1];
    const float* beta  = (const float*)d_in[2];
    const float* w1    = (const float*)d_in[3];
    const float* b1    = (const float*)d_in[4];
    const float* w2    = (const float*)d_in[5];
    const float* b2    = (const float*)d_in[6];
    float* ws   = (float*)d_ws;
    float* xd   = ws + OFF_XD;
    float* xt   = ws + OFF_XT;
    float* sims = ws + OFF_SIMS;
    float* enh  = ws + OFF_ENH;
    float* df   = ws + OFF_DF;
    float* invn = ws + OFF_INV;
    int*   mm   = (int*)(ws + OFF_MM);
    float* out  = (float*)d_out;

    k_init<<<1, 64, 0, stream>>>(mm);
    k_down<<<512, 256, 0, stream>>>(x, xd);
    k_prep<<<256, 256, 0, stream>>>(x, xd, xt, df, invn, mm);
    k_simA<<<1152, 256, 0, stream>>>(xt, invn, sims);
    k_simB<<<2048, 256, 0, stream>>>(sims, xt, df, mm, gamma, beta, enh);
    k_ffn<<<256, 256, 0, stream>>>(enh, w1, b1, w2, b2, out);
}